// Round 9
// baseline (199.457 us; speedup 1.0000x reference)
//
#include <hip/hip_runtime.h>
#include <hip/hip_bf16.h>

// ---------------------------------------------------------------------------
// qr_k (512 thr): per (b,h): X0row = emb[tok[b,0]] + PE_row0
//   q0[f] = X0row . Wq[h][:,f] + bq[f];  alpha[b,h] = q0 . bk[h]
//   r[(b*4+h)][d] = sum_f q0[f] * Wk[h][d][f]
// Block (0,0) zeroes Acc + Cnt[0..63] (Cnt[32..63] = att12's per-b handshake).
// ---------------------------------------------------------------------------
__global__ __launch_bounds__(512) void qr_k(
    const int* __restrict__ inp, const float* __restrict__ emb,
    const float* __restrict__ Wp, const float* __restrict__ bp,
    float* __restrict__ X0, float* __restrict__ r, float* __restrict__ alpha,
    float* __restrict__ Acc, int* __restrict__ Cnt)
{
    __shared__ float xs[512];
    __shared__ float red[512];
    __shared__ __align__(16) float q0s[128];
    int b = blockIdx.x, h = blockIdx.y, t = threadIdx.x;
    if (b == 0 && h == 0) {
        if (t < 32) Acc[t] = 0.f;
        else if (t < 96) Cnt[t - 32] = 0;
    }
    int tok0 = inp[b * 1024];
    {
        float v = emb[(long)tok0 * 512 + t] + ((t & 1) ? 1.0f : 0.0f);
        xs[t] = v;
        if (h == 0) X0[b * 512 + t] = v;
    }
    __syncthreads();

    int f = t & 127, dh = t >> 7;          // dh in [0,4)
    const float* wq = Wp + (long)h * 196608 + f;
    float acc = 0.f;
#pragma unroll 16
    for (int d = dh * 128; d < dh * 128 + 128; d++)
        acc += xs[d] * wq[(long)d * 384];
    red[t] = acc;
    __syncthreads();
    if (t < 128)
        q0s[t] = red[t] + red[t + 128] + red[t + 256] + red[t + 384]
               + bp[h * 384 + t];
    __syncthreads();
    if (t < 128) red[t] = q0s[t] * bp[h * 384 + 128 + t];
    __syncthreads();
    for (int w = 64; w >= 1; w >>= 1) {
        if (t < w) red[t] += red[t + w];
        __syncthreads();
    }
    if (t == 0) alpha[b * 4 + h] = red[0];

    const float4* q4 = (const float4*)q0s;
    {
        int d = t;
        const float4* wr = (const float4*)(Wp + ((long)(h * 512 + d)) * 384 + 128);
        float a2 = 0.f;
#pragma unroll 8
        for (int f4 = 0; f4 < 32; f4++) {
            float4 w = wr[f4], qq = q4[f4];
            a2 += w.x * qq.x + w.y * qq.y + w.z * qq.z + w.w * qq.w;
        }
        r[((long)(b * 4 + h)) * 512 + d] = a2;
    }
}

// ---------------------------------------------------------------------------
// xu_k (register-resident, proven): x never touches LDS.
// Grid (32 b, 16 sg), 256 thr.
// ---------------------------------------------------------------------------
__global__ __launch_bounds__(256) void xu_k(
    const int* __restrict__ inp, const float* __restrict__ emb,
    const float* __restrict__ r, const float* __restrict__ alpha,
    float* __restrict__ Tpp, float* __restrict__ Gp)
{
    __shared__ float redT[4][4][64][8];   // [wave][h][lane][jj]  32 KB
    __shared__ float redG[4][4];
    int b = blockIdx.x, sg = blockIdx.y, t = threadIdx.x;
    int wave = t >> 6, lane = t & 63;

    float rsv[4][8];
    float al[4];
#pragma unroll
    for (int h = 0; h < 4; h++) {
        const float4* rp = (const float4*)&r[((long)(b * 4 + h)) * 512 + lane * 8];
        float4 r0 = rp[0], r1 = rp[1];
        rsv[h][0] = r0.x; rsv[h][1] = r0.y; rsv[h][2] = r0.z; rsv[h][3] = r0.w;
        rsv[h][4] = r1.x; rsv[h][5] = r1.y; rsv[h][6] = r1.z; rsv[h][7] = r1.w;
        al[h] = alpha[b * 4 + h];
    }
    float w4[4];
#pragma unroll
    for (int j = 0; j < 4; j++) {
        float expo = (float)(lane * 8 + j * 2) * (1.0f / 512.0f);
        w4[j] = exp2f(-expo * 13.287712379549449f);   // 10000^-expo
    }

    float accT[4][8] = {};
    float gacc[4] = {};
    int s0 = sg * 64 + wave * 16;
#pragma unroll
    for (int g = 0; g < 4; g++) {
        float xv[4][8];
        float up[4][4];
#pragma unroll
        for (int i = 0; i < 4; i++) {
            int srow = s0 + g * 4 + i;
            int tok = inp[b * 1024 + srow];
            const float4* e = (const float4*)&emb[(long)tok * 512 + lane * 8];
            float4 e0 = e[0], e1 = e[1];
            float sf = (float)srow;
            float sv[4], cv[4];
#pragma unroll
            for (int j = 0; j < 4; j++) {
                float ang = sf * w4[j];
                sv[j] = __sinf(ang);
                cv[j] = __cosf(ang);
            }
            xv[i][0] = e0.x + sv[0]; xv[i][1] = e0.y + cv[0];
            xv[i][2] = e0.z + sv[1]; xv[i][3] = e0.w + cv[1];
            xv[i][4] = e1.x + sv[2]; xv[i][5] = e1.y + cv[2];
            xv[i][6] = e1.z + sv[3]; xv[i][7] = e1.w + cv[3];
#pragma unroll
            for (int h = 0; h < 4; h++) {
                float acc = 0.f;
#pragma unroll
                for (int jj = 0; jj < 8; jj++) acc += xv[i][jj] * rsv[h][jj];
                up[i][h] = acc;
            }
        }
#pragma unroll
        for (int off = 32; off; off >>= 1) {
#pragma unroll
            for (int i = 0; i < 4; i++)
#pragma unroll
                for (int h = 0; h < 4; h++)
                    up[i][h] += __shfl_xor(up[i][h], off);
        }
#pragma unroll
        for (int i = 0; i < 4; i++) {
#pragma unroll
            for (int h = 0; h < 4; h++) {
                float u = up[i][h] + al[h];
                gacc[h] += u;
#pragma unroll
                for (int jj = 0; jj < 8; jj++) accT[h][jj] += u * xv[i][jj];
            }
        }
    }
#pragma unroll
    for (int h = 0; h < 4; h++) {
        *(float4*)&redT[wave][h][lane][0] =
            make_float4(accT[h][0], accT[h][1], accT[h][2], accT[h][3]);
        *(float4*)&redT[wave][h][lane][4] =
            make_float4(accT[h][4], accT[h][5], accT[h][6], accT[h][7]);
    }
    if (lane == 0) {
#pragma unroll
        for (int h = 0; h < 4; h++) redG[wave][h] = gacc[h];
    }
    __syncthreads();
    long base = (long)(b * 16 + sg) * 2048;
#pragma unroll
    for (int k = 0; k < 8; k++) {
        int idx = t + k * 256;
        int h = idx >> 9, d = idx & 511;
        float v = redT[0][h][d >> 3][d & 7] + redT[1][h][d >> 3][d & 7]
                + redT[2][h][d >> 3][d & 7] + redT[3][h][d >> 3][d & 7];
        Tpp[base + idx] = v;
    }
    if (t < 4) Gp[(b * 16 + sg) * 4 + t] =
        redG[0][t] + redG[1][t] + redG[2][t] + redG[3][t];
}

// ---------------------------------------------------------------------------
// att12_k (512 thr): att1 + in-kernel per-b handshake + att2s.
// Grid (32 b, 8 jt).  Stage 1 == R7 att1 (own C0 slice, no redundancy).
// Release: all threads __threadfence() (each storer flushes its own stores),
// t0 increments CntC[b] BEFORE polling (no deadlock; 256 blocks co-resident).
// Acquire: after CntC[b]==8, read C0[b] via device-scope atomic loads.
// Stage 2 == R7 att2s.  Removes one launch gap; adds ~1 us of sync.
// ---------------------------------------------------------------------------
__global__ __launch_bounds__(512) void att12_k(
    const float* __restrict__ Tpp, const float* __restrict__ Gp,
    const float* __restrict__ Wp, const float* __restrict__ bp,
    const float* __restrict__ Wo, const float* __restrict__ bo,
    const float* __restrict__ X0, float* __restrict__ C0,
    float* __restrict__ A1, float* __restrict__ Stat, int* __restrict__ CntC)
{
    __shared__ float tps[512];
    __shared__ float red[512];
    __shared__ float c0s[512];
    int b = blockIdx.x, jt = blockIdx.y, t = threadIdx.x;
    int h = jt >> 1, e0 = (jt & 1) * 64;
    // ---- stage 1: att1 slice ----
    {
        float v = 0.f;
#pragma unroll 8
        for (int sg = 0; sg < 16; sg++)
            v += Tpp[(long)b * 32768 + sg * 2048 + h * 512 + t];
        tps[t] = v;
    }
    __syncthreads();
    {
        int e = e0 + (t & 63), rg = t >> 6;    // rg in [0,8)
        const float* wv = Wp + (long)h * 196608 + 256 + e;
        float acc = 0.f;
#pragma unroll 16
        for (int d = rg * 64; d < rg * 64 + 64; d++)
            acc += tps[d] * wv[(long)d * 384];
        red[t] = acc;
    }
    __syncthreads();
    if (t < 64) {
        float gam = 0.f;
#pragma unroll
        for (int sg = 0; sg < 16; sg++) gam += Gp[(b * 16 + sg) * 4 + h];
        float sum = red[t] + red[t + 64] + red[t + 128] + red[t + 192]
                  + red[t + 256] + red[t + 320] + red[t + 384] + red[t + 448];
        float c = 0.03125f * (sum + gam * bp[h * 384 + 256 + e0 + t]);
        C0[b * 512 + h * 128 + e0 + t] = c;
    }
    // ---- release + arrive + wait ----
    __syncthreads();
    __threadfence();                       // each thread flushes its own stores
    __syncthreads();                       // all fences retired before signal
    if (t == 0) {
        atomicAdd(&CntC[b], 1);            // arrive FIRST (no deadlock)
        while (__hip_atomic_load(&CntC[b], __ATOMIC_RELAXED,
                                 __HIP_MEMORY_SCOPE_AGENT) < 8)
            __builtin_amdgcn_s_sleep(2);
    }
    __syncthreads();
    // ---- acquire: C0[b] via coherence-point loads ----
    c0s[t] = __hip_atomic_load(&C0[b * 512 + t], __ATOMIC_RELAXED,
                               __HIP_MEMORY_SCOPE_AGENT);
    __syncthreads();
    // ---- stage 2: att2s slice ----
    int j = jt * 64 + (t & 63), rg = t >> 6;
    float acc = 0.f;
#pragma unroll 16
    for (int d = rg * 64; d < rg * 64 + 64; d++)
        acc += c0s[d] * Wo[(long)d * 512 + j];
    red[t] = acc;
    __syncthreads();
    if (t < 64) {
        int jj = jt * 64 + t;
        float a = red[t] + red[t + 64] + red[t + 128] + red[t + 192]
                + red[t + 256] + red[t + 320] + red[t + 384] + red[t + 448]
                + bo[jj] + X0[b * 512 + jj];
        A1[b * 512 + jj] = a;
        float s = a, q = a * a;
#pragma unroll
        for (int off = 32; off; off >>= 1) {
            s += __shfl_down(s, off);
            q += __shfl_down(q, off);
        }
        if (t == 0) {
            Stat[(b * 8 + jt) * 2]     = s;
            Stat[(b * 8 + jt) * 2 + 1] = q;
        }
    }
}

// ---------------------------------------------------------------------------
// ffn1_k: LN1-on-load + Hp1[ks][32][2048] = Y1[:, kchunk] @ W1[kchunk, :]
// Grid (32 jt, 16 ks), 32-row k-chunks -> 512 blocks.
// ---------------------------------------------------------------------------
__global__ __launch_bounds__(256) void ffn1_k(
    const float* __restrict__ A1, const float* __restrict__ Stat,
    const float* __restrict__ g1, const float* __restrict__ b1v,
    const float* __restrict__ W1, float* __restrict__ Hp1)
{
    __shared__ float at[32][32];
    __shared__ float mrs[32][2];
    int jt = blockIdx.x, ks = blockIdx.y, t = threadIdx.x;
    if (t < 32) {
        float s = 0.f, q = 0.f;
#pragma unroll
        for (int p8 = 0; p8 < 8; p8++) {
            s += Stat[(t * 8 + p8) * 2];
            q += Stat[(t * 8 + p8) * 2 + 1];
        }
        float mean = s * (1.0f / 512.0f);
        float var = q * (1.0f / 512.0f) - mean * mean;
        mrs[t][0] = mean;
        mrs[t][1] = rsqrtf(var + 0.001f);
    }
    __syncthreads();
    {
        int row = t >> 3, f4 = t & 7;        // 256 thr = 32 rows x 8 float4
        int col = ks * 32 + f4 * 4;
        float4 a4 = *(const float4*)&A1[(long)row * 512 + col];
        float4 g4 = *(const float4*)&g1[col];
        float4 bb = *(const float4*)&b1v[col];
        float mean = mrs[row][0], rstd = mrs[row][1];
        float4 v;
        v.x = (a4.x - mean) * rstd * g4.x + bb.x;
        v.y = (a4.y - mean) * rstd * g4.y + bb.y;
        v.z = (a4.z - mean) * rstd * g4.z + bb.z;
        v.w = (a4.w - mean) * rstd * g4.w + bb.w;
        ((float4*)at)[t] = v;
    }
    __syncthreads();
    int j = jt * 64 + (t & 63), rg = t >> 6;
    float acc[8] = {};
    const float* wp = W1 + (long)(ks * 32) * 2048 + j;
#pragma unroll 16
    for (int k = 0; k < 32; k++) {
        float wv = wp[(long)k * 2048];
#pragma unroll
        for (int rr = 0; rr < 8; rr++)
            acc[rr] += at[rg * 8 + rr][k] * wv;
    }
#pragma unroll
    for (int rr = 0; rr < 8; rr++)
        Hp1[((long)(ks * 32 + rg * 8 + rr)) * 2048 + j] = acc[rr];
}

// ---------------------------------------------------------------------------
// FFN2 partials, fused H1 = relu(sum_ks Hp1 + b1) at staging.
// Grid (8 jt, 64 ks), 32-row k-chunks -> 512 blocks.
// ---------------------------------------------------------------------------
__global__ __launch_bounds__(256) void ffn2_k(
    const float* __restrict__ Hp1, const float* __restrict__ b1,
    const float* __restrict__ W2, float* __restrict__ Hp2)
{
    __shared__ float at[32][32];
    int jt = blockIdx.x, ks2 = blockIdx.y, t = threadIdx.x;
    {
        int row = t >> 3, f4 = t & 7;
        int col4 = ks2 * 8 + f4;             // float4 index within 2048-wide row
        float4 v = ((const float4*)b1)[col4];
#pragma unroll
        for (int p = 0; p < 16; p++) {
            float4 pv = ((const float4*)Hp1)[(long)p * 16384 + row * 512 + col4];
            v.x += pv.x; v.y += pv.y; v.z += pv.z; v.w += pv.w;
        }
        v.x = fmaxf(v.x, 0.f); v.y = fmaxf(v.y, 0.f);
        v.z = fmaxf(v.z, 0.f); v.w = fmaxf(v.w, 0.f);
        ((float4*)at)[t] = v;
    }
    __syncthreads();
    int j = jt * 64 + (t & 63), rg = t >> 6;
    float acc[8] = {};
    const float* wp = W2 + (long)(ks2 * 32) * 512 + j;
#pragma unroll 16
    for (int k = 0; k < 32; k++) {
        float wv = wp[(long)k * 512];
#pragma unroll
        for (int rr = 0; rr < 8; rr++)
            acc[rr] += at[rg * 8 + rr][k] * wv;
    }
#pragma unroll
    for (int rr = 0; rr < 8; rr++)
        Hp2[((long)(ks2 * 32 + rg * 8 + rr)) * 512 + j] = acc[rr];
}

// ---------------------------------------------------------------------------
// headp3_k (512 thr): Y1 recompute (LN1) + LN2 + head partial + atomic finish.
// Grid (32 b, 8 jt).
// ---------------------------------------------------------------------------
__global__ __launch_bounds__(512) void headp3_k(
    const float* __restrict__ Hp2, const float* __restrict__ b2,
    const float* __restrict__ A1, const float* __restrict__ Stat,
    const float* __restrict__ g1v, const float* __restrict__ b1v,
    const float* __restrict__ g2v, const float* __restrict__ b2v,
    const float* __restrict__ Wh, const float* __restrict__ bh,
    const float* __restrict__ Wf, const float* __restrict__ bf,
    float* __restrict__ Acc, int* __restrict__ Cnt, float* __restrict__ out)
{
    __shared__ float xs[512];
    __shared__ float red[512];
    __shared__ float sd[16];
    __shared__ float mr[2];
    int b = blockIdx.x, jt = blockIdx.y, t = threadIdx.x;
    int wave = t >> 6;
    if (t == 0) {
        float s = 0.f, q = 0.f;
#pragma unroll
        for (int p8 = 0; p8 < 8; p8++) {
            s += Stat[(b * 8 + p8) * 2];
            q += Stat[(b * 8 + p8) * 2 + 1];
        }
        float mean = s * (1.0f / 512.0f);
        mr[0] = mean;
        mr[1] = rsqrtf(q * (1.0f / 512.0f) - mean * mean + 0.001f);
    }
    __syncthreads();
    float mean1 = mr[0], rstd1 = mr[1];
    float v;
    {
        float y1 = (A1[b * 512 + t] - mean1) * rstd1 * g1v[t] + b1v[t];
        v = b2[t] + y1;
#pragma unroll 16
        for (int ks = 0; ks < 64; ks++)
            v += Hp2[((long)(ks * 32 + b)) * 512 + t];
    }
    float s = v;
#pragma unroll
    for (int off = 32; off; off >>= 1) s += __shfl_down(s, off);
    if ((t & 63) == 0) sd[wave] = s;
    __syncthreads();
    float mean = (sd[0] + sd[1] + sd[2] + sd[3]
                + sd[4] + sd[5] + sd[6] + sd[7]) * (1.0f / 512.0f);
    float d0 = v - mean;
    float v2 = d0 * d0;
#pragma unroll
    for (int off = 32; off; off >>= 1) v2 += __shfl_down(v2, off);
    if ((t & 63) == 0) sd[8 + wave] = v2;
    __syncthreads();
    float var = (sd[8] + sd[9] + sd[10] + sd[11]
               + sd[12] + sd[13] + sd[14] + sd[15]) * (1.0f / 512.0f);
    float rstd = rsqrtf(var + 0.001f);
    xs[t] = d0 * rstd * g2v[t] + b2v[t];
    __syncthreads();

    int j = jt * 64 + (t & 63), rg = t >> 6;
    const float* w = Wh + j;
    float acc = 0.f;
#pragma unroll 16
    for (int d = rg * 64; d < rg * 64 + 64; d++)
        acc += xs[d] * w[(long)d * 512];
    red[t] = acc;
    __syncthreads();
    if (t < 64) {
        int jj = jt * 64 + t;
        float hid = red[t] + red[t + 64] + red[t + 128] + red[t + 192]
                  + red[t + 256] + red[t + 320] + red[t + 384] + red[t + 448]
                  + bh[jj];
        hid = fmaxf(hid, 0.f);
        float p = hid * Wf[jj];
#pragma unroll
        for (int off = 32; off; off >>= 1) p += __shfl_down(p, off);
        if (t == 0) {
            atomicAdd(&Acc[b], p);
            __threadfence();
            int old = atomicAdd(&Cnt[b], 1);
            if (old == 7) {
                float tot = atomicAdd(&Acc[b], 0.0f);
                float logit = tot + bf[0];
                out[b] = logit;
                out[32 + b] = 1.f / (1.f + expf(-logit));
            }
        }
    }
}

// ---------------------------------------------------------------------------
extern "C" void kernel_launch(void* const* d_in, const int* in_sizes, int n_in,
                              void* d_out, int out_size, void* d_ws, size_t ws_size,
                              hipStream_t stream)
{
    const int*   inputs = (const int*)  d_in[0];
    const float* emb    = (const float*)d_in[1];
    const float* Wp     = (const float*)d_in[2];
    const float* bp     = (const float*)d_in[3];
    const float* Wo     = (const float*)d_in[4];
    const float* bo     = (const float*)d_in[5];
    const float* ln1_g  = (const float*)d_in[6];
    const float* ln1_b  = (const float*)d_in[7];
    const float* W1     = (const float*)d_in[8];
    const float* b1     = (const float*)d_in[9];
    const float* W2     = (const float*)d_in[10];
    const float* b2     = (const float*)d_in[11];
    const float* ln2_g  = (const float*)d_in[12];
    const float* ln2_b  = (const float*)d_in[13];
    const float* Wh     = (const float*)d_in[14];
    const float* bh     = (const float*)d_in[15];
    const float* Wf     = (const float*)d_in[16];
    const float* bf     = (const float*)d_in[17];
    float* out = (float*)d_out;

    char* p = (char*)d_ws;
    float* X0    = (float*)p;  p += 65536;      // (32,512)
    float* r     = (float*)p;  p += 262144;     // (128,512)
    float* alpha = (float*)p;  p += 1024;       // (128)+pad
    float* Gp    = (float*)p;  p += 8192;       // (32,16,4)
    float* Tpp   = (float*)p;  p += 4194304;    // (32,16,4,512)
    float* C0    = (float*)p;  p += 65536;      // (32,512)
    float* A1    = (float*)p;  p += 65536;      // (32,512)  pre-LN1
    float* Stat  = (float*)p;  p += 2048;       // (32,8,2)
    float* Acc   = (float*)p;  p += 512;        // (32)+pad
    int*   Cnt   = (int*)p;    p += 512;        // (64)+pad: [0..31] head, [32..63] att12
    float* Hp1   = (float*)p;  p += 4194304;    // (16,32,2048)
    float* Hp2   = (float*)p;  p += 4194304;    // (64,32,512)

    qr_k<<<dim3(32, 4), 512, 0, stream>>>(inputs, emb, Wp, bp, X0, r, alpha,
                                          Acc, Cnt);
    xu_k<<<dim3(32, 16), 256, 0, stream>>>(inputs, emb, r, alpha, Tpp, Gp);
    att12_k<<<dim3(32, 8), 512, 0, stream>>>(Tpp, Gp, Wp, bp, Wo, bo, X0,
                                             C0, A1, Stat, Cnt + 32);
    ffn1_k<<<dim3(32, 16), 256, 0, stream>>>(A1, Stat, ln1_g, ln1_b, W1, Hp1);
    ffn2_k<<<dim3(8, 64), 256, 0, stream>>>(Hp1, b1, W2, Hp2);
    headp3_k<<<dim3(32, 8), 512, 0, stream>>>(Hp2, b2, A1, Stat,
                                              ln1_g, ln1_b, ln2_g, ln2_b,
                                              Wh, bh, Wf, bf, Acc, Cnt, out);
}

// Round 10
// 159.707 us; speedup vs baseline: 1.2489x; 1.2489x over previous
//
#include <hip/hip_runtime.h>
#include <hip/hip_bf16.h>

// ---------------------------------------------------------------------------
// qr_k (512 thr): per (b,h): X0row = emb[tok[b,0]] + PE_row0
//   q0[f] = X0row . Wq[h][:,f] + bq[f];  alpha[b,h] = q0 . bk[h]
//   r[(b*4+h)][d] = sum_f q0[f] * Wk[h][d][f]
// Grid (4 h, 32 b): same-h blocks co-XCD (stride 4 -> 2 XCDs) for Wp[h] reuse.
// Phase-A loop 8-deep load-batched.  Block (0,0) zeroes Acc/Cnt.
// ---------------------------------------------------------------------------
__global__ __launch_bounds__(512) void qr_k(
    const int* __restrict__ inp, const float* __restrict__ emb,
    const float* __restrict__ Wp, const float* __restrict__ bp,
    float* __restrict__ X0, float* __restrict__ r, float* __restrict__ alpha,
    float* __restrict__ Acc, int* __restrict__ Cnt)
{
    __shared__ float xs[512];
    __shared__ float red[512];
    __shared__ __align__(16) float q0s[128];
    int h = blockIdx.x, b = blockIdx.y, t = threadIdx.x;
    if (b == 0 && h == 0) {
        if (t < 32) Acc[t] = 0.f;
        else if (t < 64) Cnt[t - 32] = 0;
    }
    int tok0 = inp[b * 1024];
    {
        float v = emb[(long)tok0 * 512 + t] + ((t & 1) ? 1.0f : 0.0f);
        xs[t] = v;
        if (h == 0) X0[b * 512 + t] = v;
    }
    __syncthreads();

    int f = t & 127, dh = t >> 7;          // dh in [0,4)
    const float* wq = Wp + (long)h * 196608 + f;
    float acc = 0.f;
#pragma unroll
    for (int d8 = 0; d8 < 16; d8++) {
        int d0 = dh * 128 + d8 * 8;
        float wb[8];
#pragma unroll
        for (int i = 0; i < 8; i++) wb[i] = wq[(long)(d0 + i) * 384];
#pragma unroll
        for (int i = 0; i < 8; i++) acc += xs[d0 + i] * wb[i];
    }
    red[t] = acc;
    __syncthreads();
    if (t < 128)
        q0s[t] = red[t] + red[t + 128] + red[t + 256] + red[t + 384]
               + bp[h * 384 + t];
    __syncthreads();
    if (t < 128) red[t] = q0s[t] * bp[h * 384 + 128 + t];
    __syncthreads();
    for (int w = 64; w >= 1; w >>= 1) {
        if (t < w) red[t] += red[t + w];
        __syncthreads();
    }
    if (t == 0) alpha[b * 4 + h] = red[0];

    const float4* q4 = (const float4*)q0s;
    {
        int d = t;
        const float4* wr = (const float4*)(Wp + ((long)(h * 512 + d)) * 384 + 128);
        float a2 = 0.f;
#pragma unroll 8
        for (int f4 = 0; f4 < 32; f4++) {
            float4 w = wr[f4], qq = q4[f4];
            a2 += w.x * qq.x + w.y * qq.y + w.z * qq.z + w.w * qq.w;
        }
        r[((long)(b * 4 + h)) * 512 + d] = a2;
    }
}

// ---------------------------------------------------------------------------
// xu_k (register-resident, proven): x never touches LDS.
// Grid (32 b, 16 sg), 256 thr.
// ---------------------------------------------------------------------------
__global__ __launch_bounds__(256) void xu_k(
    const int* __restrict__ inp, const float* __restrict__ emb,
    const float* __restrict__ r, const float* __restrict__ alpha,
    float* __restrict__ Tpp, float* __restrict__ Gp)
{
    __shared__ float redT[4][4][64][8];   // [wave][h][lane][jj]  32 KB
    __shared__ float redG[4][4];
    int b = blockIdx.x, sg = blockIdx.y, t = threadIdx.x;
    int wave = t >> 6, lane = t & 63;

    float rsv[4][8];
    float al[4];
#pragma unroll
    for (int h = 0; h < 4; h++) {
        const float4* rp = (const float4*)&r[((long)(b * 4 + h)) * 512 + lane * 8];
        float4 r0 = rp[0], r1 = rp[1];
        rsv[h][0] = r0.x; rsv[h][1] = r0.y; rsv[h][2] = r0.z; rsv[h][3] = r0.w;
        rsv[h][4] = r1.x; rsv[h][5] = r1.y; rsv[h][6] = r1.z; rsv[h][7] = r1.w;
        al[h] = alpha[b * 4 + h];
    }
    float w4[4];
#pragma unroll
    for (int j = 0; j < 4; j++) {
        float expo = (float)(lane * 8 + j * 2) * (1.0f / 512.0f);
        w4[j] = exp2f(-expo * 13.287712379549449f);   // 10000^-expo
    }

    float accT[4][8] = {};
    float gacc[4] = {};
    int s0 = sg * 64 + wave * 16;
#pragma unroll
    for (int g = 0; g < 4; g++) {
        float xv[4][8];
        float up[4][4];
#pragma unroll
        for (int i = 0; i < 4; i++) {
            int srow = s0 + g * 4 + i;
            int tok = inp[b * 1024 + srow];
            const float4* e = (const float4*)&emb[(long)tok * 512 + lane * 8];
            float4 e0 = e[0], e1 = e[1];
            float sf = (float)srow;
            float sv[4], cv[4];
#pragma unroll
            for (int j = 0; j < 4; j++) {
                float ang = sf * w4[j];
                sv[j] = __sinf(ang);
                cv[j] = __cosf(ang);
            }
            xv[i][0] = e0.x + sv[0]; xv[i][1] = e0.y + cv[0];
            xv[i][2] = e0.z + sv[1]; xv[i][3] = e0.w + cv[1];
            xv[i][4] = e1.x + sv[2]; xv[i][5] = e1.y + cv[2];
            xv[i][6] = e1.z + sv[3]; xv[i][7] = e1.w + cv[3];
#pragma unroll
            for (int h = 0; h < 4; h++) {
                float acc = 0.f;
#pragma unroll
                for (int jj = 0; jj < 8; jj++) acc += xv[i][jj] * rsv[h][jj];
                up[i][h] = acc;
            }
        }
#pragma unroll
        for (int off = 32; off; off >>= 1) {
#pragma unroll
            for (int i = 0; i < 4; i++)
#pragma unroll
                for (int h = 0; h < 4; h++)
                    up[i][h] += __shfl_xor(up[i][h], off);
        }
#pragma unroll
        for (int i = 0; i < 4; i++) {
#pragma unroll
            for (int h = 0; h < 4; h++) {
                float u = up[i][h] + al[h];
                gacc[h] += u;
#pragma unroll
                for (int jj = 0; jj < 8; jj++) accT[h][jj] += u * xv[i][jj];
            }
        }
    }
#pragma unroll
    for (int h = 0; h < 4; h++) {
        *(float4*)&redT[wave][h][lane][0] =
            make_float4(accT[h][0], accT[h][1], accT[h][2], accT[h][3]);
        *(float4*)&redT[wave][h][lane][4] =
            make_float4(accT[h][4], accT[h][5], accT[h][6], accT[h][7]);
    }
    if (lane == 0) {
#pragma unroll
        for (int h = 0; h < 4; h++) redG[wave][h] = gacc[h];
    }
    __syncthreads();
    long base = (long)(b * 16 + sg) * 2048;
#pragma unroll
    for (int k = 0; k < 8; k++) {
        int idx = t + k * 256;
        int h = idx >> 9, d = idx & 511;
        float v = redT[0][h][d >> 3][d & 7] + redT[1][h][d >> 3][d & 7]
                + redT[2][h][d >> 3][d & 7] + redT[3][h][d >> 3][d & 7];
        Tpp[base + idx] = v;
    }
    if (t < 4) Gp[(b * 16 + sg) * 4 + t] =
        redG[0][t] + redG[1][t] + redG[2][t] + redG[3][t];
}

// ---------------------------------------------------------------------------
// att1_k (512 thr): c0[b,h*128+e] = scale*(sum_d t'[h][d] Wv[h][d][e]+gam bv)
// Grid (32 b, 8 jt): same-b blocks co-XCD (stride 32).  Wv loop 8-batched.
// ---------------------------------------------------------------------------
__global__ __launch_bounds__(512) void att1_k(
    const float* __restrict__ Tpp, const float* __restrict__ Gp,
    const float* __restrict__ Wp, const float* __restrict__ bp,
    float* __restrict__ C0)
{
    __shared__ float tps[512];
    __shared__ float red[512];
    int b = blockIdx.x, jt = blockIdx.y, t = threadIdx.x;
    int h = jt >> 1, e0 = (jt & 1) * 64;
    {
        float v = 0.f;
#pragma unroll 8
        for (int sg = 0; sg < 16; sg++)
            v += Tpp[(long)b * 32768 + sg * 2048 + h * 512 + t];
        tps[t] = v;
    }
    __syncthreads();
    int e = e0 + (t & 63), rg = t >> 6;    // rg in [0,8)
    const float* wv = Wp + (long)h * 196608 + 256 + e;
    float acc = 0.f;
#pragma unroll
    for (int d8 = 0; d8 < 8; d8++) {
        int d0 = rg * 64 + d8 * 8;
        float wb[8];
#pragma unroll
        for (int i = 0; i < 8; i++) wb[i] = wv[(long)(d0 + i) * 384];
#pragma unroll
        for (int i = 0; i < 8; i++) acc += tps[d0 + i] * wb[i];
    }
    red[t] = acc;
    __syncthreads();
    if (t < 64) {
        float gam = 0.f;
#pragma unroll
        for (int sg = 0; sg < 16; sg++) gam += Gp[(b * 16 + sg) * 4 + h];
        float sum = red[t] + red[t + 64] + red[t + 128] + red[t + 192]
                  + red[t + 256] + red[t + 320] + red[t + 384] + red[t + 448];
        float c = 0.03125f * (sum + gam * bp[h * 384 + 256 + e0 + t]);
        C0[b * 512 + h * 128 + e0 + t] = c;
    }
}

// ---------------------------------------------------------------------------
// att2s_k (512 thr): A1 = C0 @ Wo + bo + X0 and per-(b,jt) LN stats.
// Grid (32 b, 8 jt).  Wo loop 8-batched.
// ---------------------------------------------------------------------------
__global__ __launch_bounds__(512) void att2s_k(
    const float* __restrict__ C0, const float* __restrict__ Wo,
    const float* __restrict__ bo, const float* __restrict__ X0,
    float* __restrict__ A1, float* __restrict__ Stat)
{
    __shared__ float c0s[512];
    __shared__ float red[512];
    int b = blockIdx.x, jt = blockIdx.y, t = threadIdx.x;
    c0s[t] = C0[b * 512 + t];
    __syncthreads();
    int j = jt * 64 + (t & 63), rg = t >> 6;
    const float* wo = Wo + j;
    float acc = 0.f;
#pragma unroll
    for (int d8 = 0; d8 < 8; d8++) {
        int d0 = rg * 64 + d8 * 8;
        float wb[8];
#pragma unroll
        for (int i = 0; i < 8; i++) wb[i] = wo[(long)(d0 + i) * 512];
#pragma unroll
        for (int i = 0; i < 8; i++) acc += c0s[d0 + i] * wb[i];
    }
    red[t] = acc;
    __syncthreads();
    if (t < 64) {
        int jj = jt * 64 + t;
        float a = red[t] + red[t + 64] + red[t + 128] + red[t + 192]
                + red[t + 256] + red[t + 320] + red[t + 384] + red[t + 448]
                + bo[jj] + X0[b * 512 + jj];
        A1[b * 512 + jj] = a;
        float s = a, q = a * a;
#pragma unroll
        for (int off = 32; off; off >>= 1) {
            s += __shfl_down(s, off);
            q += __shfl_down(q, off);
        }
        if (t == 0) {
            Stat[(b * 8 + jt) * 2]     = s;
            Stat[(b * 8 + jt) * 2 + 1] = q;
        }
    }
}

// ---------------------------------------------------------------------------
// ffn1_k: LN1-on-load + Hp1[ks][32][2048] = Y1[:, kchunk] @ W1[kchunk, :]
// Grid (16 ks, 32 jt): same-ks blocks co-XCD (stride 16) for W1 reuse.
// W1 loop 8-batched.
// ---------------------------------------------------------------------------
__global__ __launch_bounds__(256) void ffn1_k(
    const float* __restrict__ A1, const float* __restrict__ Stat,
    const float* __restrict__ g1, const float* __restrict__ b1v,
    const float* __restrict__ W1, float* __restrict__ Hp1)
{
    __shared__ float at[32][32];
    __shared__ float mrs[32][2];
    int ks = blockIdx.x, jt = blockIdx.y, t = threadIdx.x;
    if (t < 32) {
        float s = 0.f, q = 0.f;
#pragma unroll
        for (int p8 = 0; p8 < 8; p8++) {
            s += Stat[(t * 8 + p8) * 2];
            q += Stat[(t * 8 + p8) * 2 + 1];
        }
        float mean = s * (1.0f / 512.0f);
        float var = q * (1.0f / 512.0f) - mean * mean;
        mrs[t][0] = mean;
        mrs[t][1] = rsqrtf(var + 0.001f);
    }
    __syncthreads();
    {
        int row = t >> 3, f4 = t & 7;        // 256 thr = 32 rows x 8 float4
        int col = ks * 32 + f4 * 4;
        float4 a4 = *(const float4*)&A1[(long)row * 512 + col];
        float4 g4 = *(const float4*)&g1[col];
        float4 bb = *(const float4*)&b1v[col];
        float mean = mrs[row][0], rstd = mrs[row][1];
        float4 v;
        v.x = (a4.x - mean) * rstd * g4.x + bb.x;
        v.y = (a4.y - mean) * rstd * g4.y + bb.y;
        v.z = (a4.z - mean) * rstd * g4.z + bb.z;
        v.w = (a4.w - mean) * rstd * g4.w + bb.w;
        ((float4*)at)[t] = v;
    }
    __syncthreads();
    int j = jt * 64 + (t & 63), rg = t >> 6;
    float acc[8] = {};
    const float* wp = W1 + (long)(ks * 32) * 2048 + j;
#pragma unroll
    for (int k8 = 0; k8 < 4; k8++) {
        float wb[8];
#pragma unroll
        for (int i = 0; i < 8; i++) wb[i] = wp[(long)(k8 * 8 + i) * 2048];
#pragma unroll
        for (int i = 0; i < 8; i++) {
#pragma unroll
            for (int rr = 0; rr < 8; rr++)
                acc[rr] += at[rg * 8 + rr][k8 * 8 + i] * wb[i];
        }
    }
#pragma unroll
    for (int rr = 0; rr < 8; rr++)
        Hp1[((long)(ks * 32 + rg * 8 + rr)) * 2048 + j] = acc[rr];
}

// ---------------------------------------------------------------------------
// FFN2 partials, fused H1 = relu(sum_ks Hp1 + b1) at staging.
// Grid (64 ks, 8 jt): same-ks blocks co-XCD (stride 64) for W2 reuse.
// W2 loop 8-batched.
// ---------------------------------------------------------------------------
__global__ __launch_bounds__(256) void ffn2_k(
    const float* __restrict__ Hp1, const float* __restrict__ b1,
    const float* __restrict__ W2, float* __restrict__ Hp2)
{
    __shared__ float at[32][32];
    int ks2 = blockIdx.x, jt = blockIdx.y, t = threadIdx.x;
    {
        int row = t >> 3, f4 = t & 7;
        int col4 = ks2 * 8 + f4;             // float4 index within 2048-wide row
        float4 v = ((const float4*)b1)[col4];
#pragma unroll
        for (int p = 0; p < 16; p++) {
            float4 pv = ((const float4*)Hp1)[(long)p * 16384 + row * 512 + col4];
            v.x += pv.x; v.y += pv.y; v.z += pv.z; v.w += pv.w;
        }
        v.x = fmaxf(v.x, 0.f); v.y = fmaxf(v.y, 0.f);
        v.z = fmaxf(v.z, 0.f); v.w = fmaxf(v.w, 0.f);
        ((float4*)at)[t] = v;
    }
    __syncthreads();
    int j = jt * 64 + (t & 63), rg = t >> 6;
    float acc[8] = {};
    const float* wp = W2 + (long)(ks2 * 32) * 512 + j;
#pragma unroll
    for (int k8 = 0; k8 < 4; k8++) {
        float wb[8];
#pragma unroll
        for (int i = 0; i < 8; i++) wb[i] = wp[(long)(k8 * 8 + i) * 512];
#pragma unroll
        for (int i = 0; i < 8; i++) {
#pragma unroll
            for (int rr = 0; rr < 8; rr++)
                acc[rr] += at[rg * 8 + rr][k8 * 8 + i] * wb[i];
        }
    }
#pragma unroll
    for (int rr = 0; rr < 8; rr++)
        Hp2[((long)(ks2 * 32 + rg * 8 + rr)) * 512 + j] = acc[rr];
}

// ---------------------------------------------------------------------------
// headp3_k (512 thr): Y1 recompute (LN1) + LN2 + head partial + atomic finish.
// Grid (32 b, 8 jt): same-b co-XCD.  Wh loop 8-batched.
// ---------------------------------------------------------------------------
__global__ __launch_bounds__(512) void headp3_k(
    const float* __restrict__ Hp2, const float* __restrict__ b2,
    const float* __restrict__ A1, const float* __restrict__ Stat,
    const float* __restrict__ g1v, const float* __restrict__ b1v,
    const float* __restrict__ g2v, const float* __restrict__ b2v,
    const float* __restrict__ Wh, const float* __restrict__ bh,
    const float* __restrict__ Wf, const float* __restrict__ bf,
    float* __restrict__ Acc, int* __restrict__ Cnt, float* __restrict__ out)
{
    __shared__ float xs[512];
    __shared__ float red[512];
    __shared__ float sd[16];
    __shared__ float mr[2];
    int b = blockIdx.x, jt = blockIdx.y, t = threadIdx.x;
    int wave = t >> 6;
    if (t == 0) {
        float s = 0.f, q = 0.f;
#pragma unroll
        for (int p8 = 0; p8 < 8; p8++) {
            s += Stat[(b * 8 + p8) * 2];
            q += Stat[(b * 8 + p8) * 2 + 1];
        }
        float mean = s * (1.0f / 512.0f);
        mr[0] = mean;
        mr[1] = rsqrtf(q * (1.0f / 512.0f) - mean * mean + 0.001f);
    }
    __syncthreads();
    float mean1 = mr[0], rstd1 = mr[1];
    float v;
    {
        float y1 = (A1[b * 512 + t] - mean1) * rstd1 * g1v[t] + b1v[t];
        v = b2[t] + y1;
#pragma unroll 16
        for (int ks = 0; ks < 64; ks++)
            v += Hp2[((long)(ks * 32 + b)) * 512 + t];
    }
    float s = v;
#pragma unroll
    for (int off = 32; off; off >>= 1) s += __shfl_down(s, off);
    if ((t & 63) == 0) sd[wave] = s;
    __syncthreads();
    float mean = (sd[0] + sd[1] + sd[2] + sd[3]
                + sd[4] + sd[5] + sd[6] + sd[7]) * (1.0f / 512.0f);
    float d0 = v - mean;
    float v2 = d0 * d0;
#pragma unroll
    for (int off = 32; off; off >>= 1) v2 += __shfl_down(v2, off);
    if ((t & 63) == 0) sd[8 + wave] = v2;
    __syncthreads();
    float var = (sd[8] + sd[9] + sd[10] + sd[11]
               + sd[12] + sd[13] + sd[14] + sd[15]) * (1.0f / 512.0f);
    float rstd = rsqrtf(var + 0.001f);
    xs[t] = d0 * rstd * g2v[t] + b2v[t];
    __syncthreads();

    int j = jt * 64 + (t & 63), rg = t >> 6;
    const float* w = Wh + j;
    float acc = 0.f;
#pragma unroll
    for (int d8 = 0; d8 < 8; d8++) {
        int d0i = rg * 64 + d8 * 8;
        float wb[8];
#pragma unroll
        for (int i = 0; i < 8; i++) wb[i] = w[(long)(d0i + i) * 512];
#pragma unroll
        for (int i = 0; i < 8; i++) acc += xs[d0i + i] * wb[i];
    }
    red[t] = acc;
    __syncthreads();
    if (t < 64) {
        int jj = jt * 64 + t;
        float hid = red[t] + red[t + 64] + red[t + 128] + red[t + 192]
                  + red[t + 256] + red[t + 320] + red[t + 384] + red[t + 448]
                  + bh[jj];
        hid = fmaxf(hid, 0.f);
        float p = hid * Wf[jj];
#pragma unroll
        for (int off = 32; off; off >>= 1) p += __shfl_down(p, off);
        if (t == 0) {
            atomicAdd(&Acc[b], p);
            __threadfence();
            int old = atomicAdd(&Cnt[b], 1);
            if (old == 7) {
                float tot = atomicAdd(&Acc[b], 0.0f);
                float logit = tot + bf[0];
                out[b] = logit;
                out[32 + b] = 1.f / (1.f + expf(-logit));
            }
        }
    }
}

// ---------------------------------------------------------------------------
extern "C" void kernel_launch(void* const* d_in, const int* in_sizes, int n_in,
                              void* d_out, int out_size, void* d_ws, size_t ws_size,
                              hipStream_t stream)
{
    const int*   inputs = (const int*)  d_in[0];
    const float* emb    = (const float*)d_in[1];
    const float* Wp     = (const float*)d_in[2];
    const float* bp     = (const float*)d_in[3];
    const float* Wo     = (const float*)d_in[4];
    const float* bo     = (const float*)d_in[5];
    const float* ln1_g  = (const float*)d_in[6];
    const float* ln1_b  = (const float*)d_in[7];
    const float* W1     = (const float*)d_in[8];
    const float* b1     = (const float*)d_in[9];
    const float* W2     = (const float*)d_in[10];
    const float* b2     = (const float*)d_in[11];
    const float* ln2_g  = (const float*)d_in[12];
    const float* ln2_b  = (const float*)d_in[13];
    const float* Wh     = (const float*)d_in[14];
    const float* bh     = (const float*)d_in[15];
    const float* Wf     = (const float*)d_in[16];
    const float* bf     = (const float*)d_in[17];
    float* out = (float*)d_out;

    char* p = (char*)d_ws;
    float* X0    = (float*)p;  p += 65536;      // (32,512)
    float* r     = (float*)p;  p += 262144;     // (128,512)
    float* alpha = (float*)p;  p += 1024;       // (128)+pad
    float* Gp    = (float*)p;  p += 8192;       // (32,16,4)
    float* Tpp   = (float*)p;  p += 4194304;    // (32,16,4,512)
    float* C0    = (float*)p;  p += 65536;      // (32,512)
    float* A1    = (float*)p;  p += 65536;      // (32,512)  pre-LN1
    float* Stat  = (float*)p;  p += 2048;       // (32,8,2)
    float* Acc   = (float*)p;  p += 512;        // (32)+pad
    int*   Cnt   = (int*)p;    p += 512;        // (32)+pad
    float* Hp1   = (float*)p;  p += 4194304;    // (16,32,2048)
    float* Hp2   = (float*)p;  p += 4194304;    // (64,32,512)

    qr_k<<<dim3(4, 32), 512, 0, stream>>>(inputs, emb, Wp, bp, X0, r, alpha,
                                          Acc, Cnt);
    xu_k<<<dim3(32, 16), 256, 0, stream>>>(inputs, emb, r, alpha, Tpp, Gp);
    att1_k<<<dim3(32, 8), 512, 0, stream>>>(Tpp, Gp, Wp, bp, C0);
    att2s_k<<<dim3(32, 8), 512, 0, stream>>>(C0, Wo, bo, X0, A1, Stat);
    ffn1_k<<<dim3(16, 32), 256, 0, stream>>>(A1, Stat, ln1_g, ln1_b, W1, Hp1);
    ffn2_k<<<dim3(64, 8), 256, 0, stream>>>(Hp1, b1, W2, Hp2);
    headp3_k<<<dim3(32, 8), 512, 0, stream>>>(Hp2, b2, A1, Stat,
                                              ln1_g, ln1_b, ln2_g, ln2_b,
                                              Wh, bh, Wf, bf, Acc, Cnt, out);
}